// Round 1
// baseline (8897.203 us; speedup 1.0000x reference)
//
#include <hip/hip_runtime.h>
#include <math.h>

// Problem constants
#define EMBD 400
#define HIDD 300
#define KEYD 128
#define VALD 128
#define NVOC 33
#define TT 256
#define BB 256
#define SS 512
#define WIH_LD 528          // EMB+VAL
#define GDIM 1200           // 4*HID
#define KTOT 428            // ctx(128)+h(300)
#define KPAD 432            // padded to multiple of 16 for clean unroll
#define NBLK 256            // one block per batch row -> all 256 CUs

typedef unsigned int u32x4 __attribute__((ext_vector_type(4)));
typedef unsigned int u32x2 __attribute__((ext_vector_type(2)));

__device__ __forceinline__ float bflo(unsigned int u) {
    return __uint_as_float(u << 16);
}
__device__ __forceinline__ float bfhi(unsigned int u) {
    return __uint_as_float(u & 0xffff0000u);
}
__device__ __forceinline__ unsigned short f2bf(float x) {   // RNE, no NaN inputs
    unsigned int u = __float_as_uint(x);
    return (unsigned short)((u + 0x7fffu + ((u >> 16) & 1u)) >> 16);
}
__device__ __forceinline__ float sigmoidf_(float x) {
    return 1.f / (1.f + __expf(-x));
}
__device__ __forceinline__ float tanh_f(float x) {
    float ax = fabsf(x);
    if (ax > 15.f) return x > 0.f ? 1.f : -1.f;
    float e = __expf(2.f * x);
    return (e - 1.f) / (e + 1.f);
}

// ---------------- Precompute: E2[v][j] = b_ih[j]+b_hh[j]+emb[v]·W_ih[j][:400]
__global__ __launch_bounds__(256) void p_e2(
    const float* __restrict__ emb, const float* __restrict__ Wih,
    const float* __restrict__ bih, const float* __restrict__ bhh,
    float* __restrict__ E2)
{
    __shared__ float es[EMBD];
    const int v = blockIdx.x;
    for (int i = threadIdx.x; i < EMBD; i += 256) es[i] = emb[v * EMBD + i];
    __syncthreads();
    for (int j = threadIdx.x; j < GDIM; j += 256) {
        const float* wr = &Wih[(size_t)j * WIH_LD];
        float s0 = 0.f, s1 = 0.f, s2 = 0.f, s3 = 0.f;
        for (int e = 0; e < EMBD; e += 4) {
            s0 += es[e]     * wr[e];
            s1 += es[e + 1] * wr[e + 1];
            s2 += es[e + 2] * wr[e + 2];
            s3 += es[e + 3] * wr[e + 3];
        }
        E2[v * GDIM + j] = bih[j] + bhh[j] + ((s0 + s1) + (s2 + s3));
    }
}

// ---------------- Precompute: Wtb (bf16, fused+transposed, K padded) + phi_wT
__global__ __launch_bounds__(256) void p_wt(
    const float* __restrict__ Wih, const float* __restrict__ Whh,
    const float* __restrict__ phi_w,
    unsigned short* __restrict__ Wtb, float* __restrict__ phi_wT)
{
    const int stride = gridDim.x * 256;
    for (int i = blockIdx.x * 256 + threadIdx.x; i < KPAD * GDIM; i += stride) {
        int k = i / GDIM, j = i - k * GDIM;
        float v = 0.f;
        if (k < KEYD)      v = Wih[(size_t)j * WIH_LD + EMBD + k];
        else if (k < KTOT) v = Whh[(size_t)j * HIDD + (k - KEYD)];
        Wtb[i] = f2bf(v);
    }
    for (int i = blockIdx.x * 256 + threadIdx.x; i < KEYD * HIDD; i += stride) {
        int k = i / HIDD, ii = i - k * HIDD;   // phi_w[k][ii]
        phi_wT[ii * KEYD + k] = phi_w[i];
    }
}

// ---------------- Precompute: KV -> bf16, transposed to [b][s][dim]
__global__ __launch_bounds__(1024) void p_kv(
    const float* __restrict__ keys, const float* __restrict__ values,
    unsigned short* __restrict__ kbf, unsigned short* __restrict__ vbf)
{
    size_t i = (size_t)blockIdx.x * 1024 + threadIdx.x;  // S*B*K total exactly
    int s = (int)(i >> 15);
    int r = (int)(i & 32767);
    int b = r >> 7, k = r & 127;
    size_t d = (((size_t)b * SS + s) << 7) + k;
    kbf[d] = f2bf(keys[i]);
    vbf[d] = f2bf(values[i]);
}

// ---------------- logits for one row: threads 512..1023, 16 lanes per vocab
__device__ __forceinline__ void logits33(
    int tid, int b, int t, const float* __restrict__ projw,
    const float* __restrict__ projb, float* __restrict__ out,
    const float* __restrict__ h_s, const float* __restrict__ ctx_s)
{
    if (tid >= 512) {
        const int idx = tid - 512;
        const int l = idx & 15;
        const int vs = idx >> 4;                  // 0..31
        #pragma unroll
        for (int rep = 0; rep < 2; ++rep) {
            const int v = vs + rep * 32;
            if (v < NVOC) {
                const float* pw = projw + (size_t)v * KTOT;
                float s = 0.f;
                for (int k = l; k < KTOT; k += 16) {
                    float u = (k < HIDD) ? h_s[k] : ctx_s[k - HIDD];
                    s += pw[k] * u;
                }
                #pragma unroll
                for (int off = 8; off; off >>= 1) s += __shfl_xor(s, off);
                if (l == 0)
                    out[((size_t)t * BB + b) * NVOC + v] = s + projb[v];
            }
        }
    }
}

// ---------------- attend for one row (1024 threads). OVL: overlap logits(t)
// on upper 512 threads during the q-partial phase.
template<int KVBF, int OVL>
__device__ __forceinline__ void attend1(
    const int tid, const int b, const int t,
    const float* __restrict__ keysf, const float* __restrict__ valuesf,
    const unsigned short* __restrict__ kbf, const unsigned short* __restrict__ vbf,
    const float* __restrict__ phi_wT, const float* __restrict__ phi_b,
    const float* __restrict__ projw, const float* __restrict__ projb,
    float* __restrict__ out,
    float* h_s, float* ctx_s, float* q_s, float* att, float (*qp)[KEYD],
    float (*cpart)[VALD], float* redM, float* redS, float* xin)
{
    // ---- q partial: q[k] = sum_i h[i]*phi_wT[i][k]; lower 512 threads,
    //      4 slices of 75 i's. Upper 512 do logits(t) when OVL.
    if (tid < 512) {
        const int slice = tid >> 7, k = tid & 127;
        const int i0 = slice * 75;
        float a = 0.f;
        #pragma unroll 5
        for (int i = i0; i < i0 + 75; ++i)
            a += h_s[i] * phi_wT[i * KEYD + k];
        qp[slice][k] = a;
    } else if (OVL) {
        logits33(tid, b, t, projw, projb, out, h_s, ctx_s);
    }
    __syncthreads();
    if (tid < KEYD)
        q_s[tid] = phi_b[tid] + qp[0][tid] + qp[1][tid] + qp[2][tid] + qp[3][tid];
    __syncthreads();

    // ---- energy: 64 s-groups x 16 lanes; 8 s per group
    {
        const int l16 = tid & 15, sg = tid >> 4;    // sg 0..63
        const float4* q4 = reinterpret_cast<const float4*>(q_s);
        const float4 qa = q4[l16 * 2], qb = q4[l16 * 2 + 1];
        if (KVBF) {
            const unsigned short* krow = kbf + ((size_t)b * SS) * KEYD;
            #pragma unroll
            for (int p = 0; p < 8; ++p) {
                int s = p * 64 + sg;
                const u32x4* kp = reinterpret_cast<const u32x4*>(
                    krow + (size_t)s * KEYD);
                u32x4 w = __builtin_nontemporal_load(kp + l16);
                float e = bflo(w.x) * qa.x + bfhi(w.x) * qa.y
                        + bflo(w.y) * qa.z + bfhi(w.y) * qa.w
                        + bflo(w.z) * qb.x + bfhi(w.z) * qb.y
                        + bflo(w.w) * qb.z + bfhi(w.w) * qb.w;
                e += __shfl_xor(e, 1);
                e += __shfl_xor(e, 2);
                e += __shfl_xor(e, 4);
                e += __shfl_xor(e, 8);
                if (l16 == 0) att[s] = e;
            }
        } else {
            #pragma unroll
            for (int p = 0; p < 8; ++p) {
                int s = p * 64 + sg;
                const float4* kp = reinterpret_cast<const float4*>(
                    &keysf[((size_t)s * BB + b) * KEYD]);
                float4 ka = kp[l16 * 2], kb = kp[l16 * 2 + 1];
                float e = ka.x * qa.x + ka.y * qa.y + ka.z * qa.z + ka.w * qa.w
                        + kb.x * qb.x + kb.y * qb.y + kb.z * qb.z + kb.w * qb.w;
                e += __shfl_xor(e, 1);
                e += __shfl_xor(e, 2);
                e += __shfl_xor(e, 4);
                e += __shfl_xor(e, 8);
                if (l16 == 0) att[s] = e;
            }
        }
    }
    __syncthreads();

    // ---- softmax over 512 energies (threads 0..511 own one each)
    {
        const int lane = tid & 63, wv = tid >> 6;
        float e0 = (tid < 512) ? att[tid] : -1e30f;
        float m = e0;
        #pragma unroll
        for (int off = 32; off; off >>= 1) m = fmaxf(m, __shfl_xor(m, off));
        if (tid < 512 && lane == 0) redM[wv] = m;
        __syncthreads();
        float M = redM[0];
        #pragma unroll
        for (int w = 1; w < 8; ++w) M = fmaxf(M, redM[w]);
        float p0 = (tid < 512) ? __expf(e0 - M) : 0.f;
        float ss = p0;
        #pragma unroll
        for (int off = 32; off; off >>= 1) ss += __shfl_xor(ss, off);
        if (tid < 512 && lane == 0) redS[wv] = ss;
        __syncthreads();
        float inv = 1.f / (redS[0] + redS[1] + redS[2] + redS[3]
                         + redS[4] + redS[5] + redS[6] + redS[7]);
        if (tid < 512) att[tid] = p0 * inv;
    }
    __syncthreads();

    // ---- ctx[v] = sum_s att[s]*V[s][v]: 32 s-groups x 32 lanes (4 v each)
    {
        const int v4 = tid & 31, sg = tid >> 5;     // sg 0..31
        float4 a = make_float4(0.f, 0.f, 0.f, 0.f);
        if (KVBF) {
            const unsigned short* vrow = vbf + ((size_t)b * SS) * VALD;
            #pragma unroll 4
            for (int i = 0; i < 16; ++i) {
                int s = sg * 16 + i;
                const u32x2* vp = reinterpret_cast<const u32x2*>(
                    vrow + (size_t)s * VALD);
                u32x2 w = __builtin_nontemporal_load(vp + v4);
                float wt = att[s];
                a.x += wt * bflo(w.x); a.y += wt * bfhi(w.x);
                a.z += wt * bflo(w.y); a.w += wt * bfhi(w.y);
            }
        } else {
            #pragma unroll 4
            for (int i = 0; i < 16; ++i) {
                int s = sg * 16 + i;
                float wt = att[s];
                const float4* vp = reinterpret_cast<const float4*>(
                    &valuesf[((size_t)s * BB + b) * VALD]);
                float4 v = vp[v4];
                a.x += wt * v.x; a.y += wt * v.y;
                a.z += wt * v.z; a.w += wt * v.w;
            }
        }
        *reinterpret_cast<float4*>(&cpart[sg][v4 * 4]) = a;
    }
    __syncthreads();
    if (tid < VALD) {
        float s = 0.f;
        #pragma unroll
        for (int g = 0; g < 32; ++g) s += cpart[g][tid];
        ctx_s[tid] = s;
        xin[tid] = s;      // staged for next step's gates GEMM
    }
    __syncthreads();
}

// ---------------- main body: one persistent block per batch row ------------
template<int KVBF>
__device__ __forceinline__ void decoder_body(
    const int* __restrict__ input,
    const float* __restrict__ keysf, const float* __restrict__ valuesf,
    const unsigned short* __restrict__ kbf, const unsigned short* __restrict__ vbf,
    const float* __restrict__ phi_b, const float* __restrict__ h0,
    const float* __restrict__ c0, const float* __restrict__ projw,
    const float* __restrict__ projb, const float* __restrict__ E2,
    const unsigned short* __restrict__ Wtb, const float* __restrict__ phi_wT,
    float* __restrict__ out)
{
    const int tid = threadIdx.x;
    const int b = blockIdx.x;

    __shared__ float h_s[HIDD];
    __shared__ float c_s[HIDD];
    __shared__ float ctx_s[VALD];
    __shared__ __align__(16) float xin[KPAD];        // [ctx(128) | h(300) | 0pad]
    __shared__ __align__(16) float gp[3 * GDIM];     // 3 k-slice partials, 14.4 KB
    __shared__ __align__(16) float att[SS];
    __shared__ __align__(16) float q_s[KEYD];
    __shared__ __align__(16) float qp[4][KEYD];
    __shared__ __align__(16) float cpart[32][VALD];  // 16 KB
    __shared__ float redM[8], redS[8];
    __shared__ int xv_s;

    // ---- init h, c, xin-h part, xin pad
    for (int j = tid; j < HIDD; j += 1024) {
        float hv = h0[j];
        h_s[j] = hv;
        c_s[j] = c0[j];
        xin[VALD + j] = hv;
    }
    if (tid < KPAD - KTOT) xin[KTOT + tid] = 0.f;
    __syncthreads();

    // ctx(-1) = attend(h_init); no logits overlap
    attend1<KVBF, 0>(tid, b, 0, keysf, valuesf, kbf, vbf, phi_wT, phi_b,
                     projw, projb, out, h_s, ctx_s, q_s, att, qp, cpart,
                     redM, redS, xin);

    #pragma unroll 1
    for (int t = 0; t < TT; ++t) {
        // ---- gates GEMM: gl[j] = sum_k xin[k]*Wtb[k][j]
        // 900 workers: 300 j-quads (4 j via one dwordx2) x 3 k-slices of 144.
        if (tid < 900) {
            const int c = tid / 300;
            const int q = tid - c * 300;
            const u32x2* Wp = reinterpret_cast<const u32x2*>(Wtb) + q;
            const float4* x4 = reinterpret_cast<const float4*>(xin) + c * 36;
            float a0 = 0.f, a1 = 0.f, a2 = 0.f, a3 = 0.f;
            const int kbase = c * 144;
            #pragma unroll 4
            for (int k4 = 0; k4 < 36; ++k4) {
                float4 x = x4[k4];
                const size_t kk = (size_t)(kbase + k4 * 4) * 300;
                u32x2 w0 = Wp[kk];
                u32x2 w1 = Wp[kk + 300];
                u32x2 w2 = Wp[kk + 600];
                u32x2 w3 = Wp[kk + 900];
                a0 += x.x * bflo(w0.x) + x.y * bflo(w1.x)
                    + x.z * bflo(w2.x) + x.w * bflo(w3.x);
                a1 += x.x * bfhi(w0.x) + x.y * bfhi(w1.x)
                    + x.z * bfhi(w2.x) + x.w * bfhi(w3.x);
                a2 += x.x * bflo(w0.y) + x.y * bflo(w1.y)
                    + x.z * bflo(w2.y) + x.w * bflo(w3.y);
                a3 += x.x * bfhi(w0.y) + x.y * bfhi(w1.y)
                    + x.z * bfhi(w2.y) + x.w * bfhi(w3.y);
            }
            reinterpret_cast<float4*>(gp + c * GDIM)[q] =
                make_float4(a0, a1, a2, a3);
        } else if (tid == 1023) {
            xv_s = input[t * BB + b];
        }
        __syncthreads();

        // ---- cell update (+E2 embedding gather); 300 threads, one j each
        if (tid < HIDD) {
            const int j = tid;
            const float* e2r = E2 + (size_t)xv_s * GDIM;
            float gi = gp[j]
                     + gp[GDIM + j]
                     + gp[2 * GDIM + j]            + e2r[j];
            float gf = gp[HIDD + j]
                     + gp[GDIM + HIDD + j]
                     + gp[2 * GDIM + HIDD + j]     + e2r[HIDD + j];
            float gg = gp[2 * HIDD + j]
                     + gp[GDIM + 2 * HIDD + j]
                     + gp[2 * GDIM + 2 * HIDD + j] + e2r[2 * HIDD + j];
            float go = gp[3 * HIDD + j]
                     + gp[GDIM + 3 * HIDD + j]
                     + gp[2 * GDIM + 3 * HIDD + j] + e2r[3 * HIDD + j];
            float ig = sigmoidf_(gi);
            float fg = sigmoidf_(gf);
            float gt = tanh_f(gg);
            float og = sigmoidf_(go);
            float cn = fg * c_s[j] + ig * gt;
            c_s[j] = cn;
            float hv = og * tanh_f(cn);
            h_s[j] = hv;
            xin[VALD + j] = hv;
        }
        __syncthreads();

        // ---- attend(h(t)) -> ctx(t), with logits(t) overlapped on upper 512.
        // Last step: logits only (ctx(255) unused).
        if (t < TT - 1) {
            attend1<KVBF, 1>(tid, b, t, keysf, valuesf, kbf, vbf, phi_wT,
                             phi_b, projw, projb, out, h_s, ctx_s, q_s, att,
                             qp, cpart, redM, redS, xin);
        } else {
            logits33(tid, b, t, projw, projb, out, h_s, ctx_s);
        }
    }
}

__global__ void __launch_bounds__(1024, 4) decoder_bf(
    const int* input, const float* keysf, const float* valuesf,
    const unsigned short* kbf, const unsigned short* vbf,
    const float* phi_b, const float* h0, const float* c0,
    const float* projw, const float* projb, const float* E2,
    const unsigned short* Wtb, const float* phi_wT, float* out)
{
    decoder_body<1>(input, keysf, valuesf, kbf, vbf, phi_b, h0, c0,
                    projw, projb, E2, Wtb, phi_wT, out);
}

__global__ void __launch_bounds__(1024, 4) decoder_f32(
    const int* input, const float* keysf, const float* valuesf,
    const unsigned short* kbf, const unsigned short* vbf,
    const float* phi_b, const float* h0, const float* c0,
    const float* projw, const float* projb, const float* E2,
    const unsigned short* Wtb, const float* phi_wT, float* out)
{
    decoder_body<0>(input, keysf, valuesf, kbf, vbf, phi_b, h0, c0,
                    projw, projb, E2, Wtb, phi_wT, out);
}

// =====================================================================
extern "C" void kernel_launch(void* const* d_in, const int* in_sizes, int n_in,
                              void* d_out, int out_size, void* d_ws, size_t ws_size,
                              hipStream_t stream)
{
    const int*   input     = (const int*)  d_in[0];
    const float* keys      = (const float*)d_in[1];
    const float* values    = (const float*)d_in[2];
    const float* embedding = (const float*)d_in[3];
    const float* phi_w     = (const float*)d_in[4];
    const float* phi_b     = (const float*)d_in[5];
    const float* h0        = (const float*)d_in[6];
    const float* c0        = (const float*)d_in[7];
    const float* W_ih      = (const float*)d_in[8];
    const float* b_ih      = (const float*)d_in[9];
    const float* W_hh      = (const float*)d_in[10];
    const float* b_hh      = (const float*)d_in[11];
    const float* proj_w    = (const float*)d_in[12];
    const float* proj_b    = (const float*)d_in[13];
    float* out = (float*)d_out;

    char* base = (char*)d_ws;
    size_t off = 0;
    auto alloc = [&](size_t bytes) {
        size_t o = off;
        off = (off + bytes + 255) & ~(size_t)255;
        return o;
    };
    size_t oE2   = alloc((size_t)NVOC * GDIM * 4);       // 158 KB
    size_t oPhi  = alloc((size_t)HIDD * KEYD * 4);       // 154 KB
    size_t oWtb  = alloc((size_t)KPAD * GDIM * 2);       // 1.04 MB
    size_t small_total = off;
    size_t oKbf  = alloc((size_t)SS * BB * KEYD * 2);    // 33.6 MB
    size_t oVbf  = alloc((size_t)SS * BB * VALD * 2);    // 33.6 MB
    size_t full_total = off;

    float* E2 = (float*)(base + oE2);
    float* phi_wT = (float*)(base + oPhi);
    unsigned short* Wtb = (unsigned short*)(base + oWtb);
    unsigned short* kbf = (unsigned short*)(base + oKbf);
    unsigned short* vbf = (unsigned short*)(base + oVbf);

    const bool kvbf = (ws_size >= full_total);
    (void)small_total;

    p_e2<<<NVOC, 256, 0, stream>>>(embedding, W_ih, b_ih, b_hh, E2);
    p_wt<<<2048, 256, 0, stream>>>(W_ih, W_hh, phi_w, Wtb, phi_wT);

    if (kvbf) {
        p_kv<<<(SS * BB * KEYD) / 1024, 1024, 0, stream>>>(keys, values, kbf, vbf);
        decoder_bf<<<NBLK, 1024, 0, stream>>>(
            input, keys, values, kbf, vbf, phi_b, h0, c0,
            proj_w, proj_b, E2, Wtb, phi_wT, out);
    } else {
        decoder_f32<<<NBLK, 1024, 0, stream>>>(
            input, keys, values, (const unsigned short*)nullptr,
            (const unsigned short*)nullptr, phi_b, h0, c0,
            proj_w, proj_b, E2, Wtb, phi_wT, out);
    }
}